// Round 7
// baseline (4457.187 us; speedup 1.0000x reference)
//
#include <hip/hip_runtime.h>
#include <hip/hip_bf16.h>

#define NB 2
#define NS 2048
#define ND 1024
#define NH 16
#define NE 64

// ---------------------------------------------------------------------------
// WT[w][h][e][k] = W_w[h][k][e]  (f32 -> f32), so GEMM B operand is [n][k].
// grid (256, 3), block 256. blockIdx.x = h*16 + kt
// ---------------------------------------------------------------------------
__global__ __launch_bounds__(256) void transpose_w_f32(const float* __restrict__ Wq,
                                                       const float* __restrict__ Wk,
                                                       const float* __restrict__ Wv,
                                                       float* __restrict__ WT) {
  const int w = blockIdx.y;
  const float* W = (w == 0) ? Wq : ((w == 1) ? Wk : Wv);
  const int h = blockIdx.x >> 4, kt = blockIdx.x & 15;
  __shared__ float tile[64][65];
  const int tid = threadIdx.x;
#pragma unroll
  for (int i = 0; i < 16; ++i) {
    const int idx = i * 256 + tid, kl = idx >> 6, e = idx & 63;
    tile[kl][e] = W[((size_t)h * ND + kt * 64 + kl) * NE + e];
  }
  __syncthreads();
#pragma unroll
  for (int i = 0; i < 16; ++i) {
    const int idx = i * 256 + tid, el = idx >> 6, kl = idx & 63;
    WT[((size_t)w * NH * NE + h * NE + el) * ND + kt * 64 + kl] = tile[kl][el];
  }
}

// ---------------------------------------------------------------------------
// Tiled f32 GEMM: X[4096][1024] x WT_w[n][k] -> Q/K/V f32 [B,H,S,E]
// grid (32, 128, 3), block 256, tile 32x32, BK=32, 2x2 outputs/thread.
// ---------------------------------------------------------------------------
__global__ __launch_bounds__(256) void qkv_gemm_simple(const float* __restrict__ X,
                                                       const float* __restrict__ WT,
                                                       float* __restrict__ Qo,
                                                       float* __restrict__ Ko,
                                                       float* __restrict__ Vo) {
  const int w = blockIdx.z;
  const float* Bw = WT + (size_t)w * ND * ND;
  const int n0 = blockIdx.x * 32, m0 = blockIdx.y * 32;
  __shared__ float As[32][36], Bs[32][36];
  const int t = threadIdx.x;
  const int lr = t >> 3, lc4 = (t & 7) * 4;
  const int tm = (t >> 4) * 2, tn = (t & 15) * 2;
  float acc[2][2] = {};
  for (int k0 = 0; k0 < ND; k0 += 32) {
    __syncthreads();
    *(float4*)&As[lr][lc4] = *(const float4*)&X [(size_t)(m0 + lr) * ND + k0 + lc4];
    *(float4*)&Bs[lr][lc4] = *(const float4*)&Bw[(size_t)(n0 + lr) * ND + k0 + lc4];
    __syncthreads();
#pragma unroll
    for (int kk = 0; kk < 32; ++kk) {
      const float a0 = As[tm][kk], a1 = As[tm + 1][kk];
      const float b0 = Bs[tn][kk], b1 = Bs[tn + 1][kk];
      acc[0][0] += a0 * b0; acc[0][1] += a0 * b1;
      acc[1][0] += a1 * b0; acc[1][1] += a1 * b1;
    }
  }
  float* O = (w == 0) ? Qo : ((w == 1) ? Ko : Vo);
#pragma unroll
  for (int i = 0; i < 2; ++i)
#pragma unroll
    for (int j = 0; j < 2; ++j) {
      const int m = m0 + tm + i, n = n0 + tn + j;
      const int b = m >> 11, s = m & 2047, h = n >> 6, e = n & 63;
      O[(((size_t)b * NH + h) * NS + s) * NE + e] = acc[i][j];
    }
}

// ---------------------------------------------------------------------------
// Causal attention, textbook online softmax, all f32 (round-5 verified).
// One block = 128 consecutive s for one (b,h). K/V staged in 64-row LDS tiles.
// ---------------------------------------------------------------------------
__global__ __launch_bounds__(128) void attn_naive(const float* __restrict__ Q,
                                                  const float* __restrict__ K,
                                                  const float* __restrict__ V,
                                                  float* __restrict__ AO) {
  const int blk = blockIdx.x;            // bh*16 + schunk
  const int bh = blk >> 4, sc = blk & 15;
  const int t = threadIdx.x;             // 0..127
  const int s = sc * 128 + t;
  const float* Qr = Q + ((size_t)bh * NS + s) * NE;
  const float* Kb = K + (size_t)bh * NS * NE;
  const float* Vb = V + (size_t)bh * NS * NE;
  __shared__ float Ks[64][64], Vs[64][64];
  float q[NE], o[NE];
#pragma unroll
  for (int e = 0; e < NE; ++e) { q[e] = Qr[e]; o[e] = 0.f; }
  float m = -1.0e30f, l = 0.f;
  const int ntile = sc * 2 + 2;          // covers t <= s for this block
  for (int tile = 0; tile < ntile; ++tile) {
    __syncthreads();
#pragma unroll
    for (int i = 0; i < 32; ++i) {
      const int idx = i * 128 + t;
      Ks[idx >> 6][idx & 63] = Kb[(size_t)tile * 4096 + idx];
      Vs[idx >> 6][idx & 63] = Vb[(size_t)tile * 4096 + idx];
    }
    __syncthreads();
    const int rmax = min(63, s - tile * 64);   // causal: global t <= s
    for (int r = 0; r <= rmax; ++r) {
      float d = 0.f;
#pragma unroll
      for (int e = 0; e < NE; ++e) d += q[e] * Ks[r][e];
      d *= 0.125f;
      const float mn = fmaxf(m, d);
      const float c = __expf(m - mn);
      const float p = __expf(d - mn);
      l = l * c + p;
      m = mn;
#pragma unroll
      for (int e = 0; e < NE; ++e) o[e] = o[e] * c + p * Vs[r][e];
    }
  }
  const float inv = 1.f / l;
  float* Ao = AO + ((size_t)(bh >> 4) * NS + s) * ND + (bh & 15) * NE;
#pragma unroll
  for (int e = 0; e < NE; ++e) Ao[e] = o[e] * inv;
}

// ---------------------------------------------------------------------------
// Tiled f32 GEMM: AO[4096][1024] x Wproj[n][k] -> out f32 [4096][1024]
// ---------------------------------------------------------------------------
__global__ __launch_bounds__(256) void proj_gemm_simple(const float* __restrict__ A,
                                                        const float* __restrict__ Wp,
                                                        float* __restrict__ Y) {
  const int n0 = blockIdx.x * 32, m0 = blockIdx.y * 32;
  __shared__ float As[32][36], Bs[32][36];
  const int t = threadIdx.x;
  const int lr = t >> 3, lc4 = (t & 7) * 4;
  const int tm = (t >> 4) * 2, tn = (t & 15) * 2;
  float acc[2][2] = {};
  for (int k0 = 0; k0 < ND; k0 += 32) {
    __syncthreads();
    *(float4*)&As[lr][lc4] = *(const float4*)&A [(size_t)(m0 + lr) * ND + k0 + lc4];
    *(float4*)&Bs[lr][lc4] = *(const float4*)&Wp[(size_t)(n0 + lr) * ND + k0 + lc4];
    __syncthreads();
#pragma unroll
    for (int kk = 0; kk < 32; ++kk) {
      const float a0 = As[tm][kk], a1 = As[tm + 1][kk];
      const float b0 = Bs[tn][kk], b1 = Bs[tn + 1][kk];
      acc[0][0] += a0 * b0; acc[0][1] += a0 * b1;
      acc[1][0] += a1 * b0; acc[1][1] += a1 * b1;
    }
  }
#pragma unroll
  for (int i = 0; i < 2; ++i)
#pragma unroll
    for (int j = 0; j < 2; ++j)
      Y[(size_t)(m0 + tm + i) * ND + n0 + tn + j] = acc[i][j];
}

extern "C" void kernel_launch(void* const* d_in, const int* in_sizes, int n_in,
                              void* d_out, int out_size, void* d_ws, size_t ws_size,
                              hipStream_t stream) {
  const float* x  = (const float*)d_in[0];
  const float* Wq = (const float*)d_in[1];
  const float* Wk = (const float*)d_in[2];
  const float* Wv = (const float*)d_in[3];
  const float* Wp = (const float*)d_in[4];
  float* out = (float*)d_out;            // reference output dtype is FLOAT32

  const size_t SZ = (size_t)NB * NH * NS * NE;   // 4,194,304
  float* WT = (float*)d_ws;                      // 3*ND*ND
  float* Q  = WT + (size_t)3 * ND * ND;
  float* K  = Q + SZ;
  float* V  = K + SZ;
  float* AO = V + SZ;                            // [B,S,D] f32

  hipLaunchKernelGGL(transpose_w_f32, dim3(256, 3), dim3(256), 0, stream, Wq, Wk, Wv, WT);
  hipLaunchKernelGGL(qkv_gemm_simple, dim3(32, 128, 3), dim3(256), 0, stream, x, WT, Q, K, V);
  hipLaunchKernelGGL(attn_naive, dim3(NB * NH * 16), dim3(128), 0, stream, Q, K, V, AO);
  hipLaunchKernelGGL(proj_gemm_simple, dim3(32, 128), dim3(256), 0, stream, AO, Wp, out);
}

// Round 8
// 230.813 us; speedup vs baseline: 19.3108x; 19.3108x over previous
//
#include <hip/hip_runtime.h>
#include <hip/hip_bf16.h>

typedef __attribute__((ext_vector_type(8))) short short8;
typedef __attribute__((ext_vector_type(4))) float f32x4;
typedef __hip_bfloat16 bf16;

#define NB 2
#define NS 2048
#define ND 1024
#define NH 16
#define NE 64

// async global->LDS, 16B per lane; LDS dest = wave-uniform base + lane*16
#define ASYNC16(g, l) __builtin_amdgcn_global_load_lds( \
    (const __attribute__((address_space(1))) void*)(g), \
    (__attribute__((address_space(3))) void*)(l), 16, 0, 0)

__device__ __forceinline__ unsigned short bf16b(float x) {
  __hip_bfloat16 h = __float2bfloat16(x);
  unsigned short u;
  __builtin_memcpy(&u, &h, 2);
  return u;
}

// ---------------------------------------------------------------------------
// f32 -> bf16 elementwise ingest. 8 elems/thread.
// ---------------------------------------------------------------------------
__global__ __launch_bounds__(256) void ingest_f32_bf16(const float* __restrict__ src,
                                                       bf16* __restrict__ dst, int n) {
  int i = (blockIdx.x * 256 + threadIdx.x) * 8;
  if (i >= n) return;
  const float4 a = *(const float4*)(src + i);
  const float4 b = *(const float4*)(src + i + 4);
  *(ushort4*)(dst + i)     = make_ushort4(bf16b(a.x), bf16b(a.y), bf16b(a.z), bf16b(a.w));
  *(ushort4*)(dst + i + 4) = make_ushort4(bf16b(b.x), bf16b(b.y), bf16b(b.z), bf16b(b.w));
}

// ---------------------------------------------------------------------------
// WT[w][h][e][k] = W_w[h][k][e]  (f32 -> bf16): GEMM B operand is [n][k].
// grid (256, 3), block 256. blockIdx.x = h*16 + kt
// ---------------------------------------------------------------------------
__global__ __launch_bounds__(256) void transpose_w(const float* __restrict__ Wq,
                                                   const float* __restrict__ Wk,
                                                   const float* __restrict__ Wv,
                                                   bf16* __restrict__ WT) {
  const int w = blockIdx.y;
  const float* W = (w == 0) ? Wq : ((w == 1) ? Wk : Wv);
  const int h = blockIdx.x >> 4, kt = blockIdx.x & 15;
  __shared__ bf16 tile[64][65];
  const int tid = threadIdx.x;
#pragma unroll
  for (int i = 0; i < 16; ++i) {
    const int idx = i * 256 + tid, kl = idx >> 6, e = idx & 63;
    tile[kl][e] = __float2bfloat16(W[((size_t)h * ND + kt * 64 + kl) * NE + e]);
  }
  __syncthreads();
#pragma unroll
  for (int i = 0; i < 16; ++i) {
    const int idx = i * 256 + tid, el = idx >> 6, kl = idx & 63;
    WT[((size_t)w * NH * NE + h * NE + el) * ND + kt * 64 + kl] = tile[kl][el];
  }
}

// ---------------------------------------------------------------------------
// QKV projection: Xb[4096][1024] x WT_w[n][k] -> Q/K [B,H,S,E], V^T [B,H,E,S]
// grid (8, 32, 3) ; block 256 (4 waves 2x2), tile 128x128, BK=32, mfma 16x16x32.
// ---------------------------------------------------------------------------
__global__ __launch_bounds__(256) void qkv_gemm(const bf16* __restrict__ X,
                                                const bf16* __restrict__ WT,
                                                bf16* __restrict__ Qo,
                                                bf16* __restrict__ Ko,
                                                bf16* __restrict__ Vo) {
  const int w = blockIdx.z;
  const bf16* Bm = WT + (size_t)w * (NH * NE * ND);
  const int n0 = blockIdx.x * 128, m0 = blockIdx.y * 128;
  __shared__ __align__(16) bf16 As[128 * 32];
  __shared__ __align__(16) bf16 Bs[128 * 32];
  const int tid = threadIdx.x;
  const int lane = tid & 63, wid = tid >> 6;
  const int wm = wid >> 1, wn = wid & 1;
  const int g = lane >> 4, c = lane & 15;
  const int row4 = tid >> 2, kc = (tid & 3) * 8;
  f32x4 acc[4][4] = {};
  for (int k0 = 0; k0 < ND; k0 += 32) {
    __syncthreads();
    ASYNC16(X + (size_t)(m0 + row4) * ND + k0 + kc, As + wid * 512);
    ASYNC16(X + (size_t)(m0 + 64 + row4) * ND + k0 + kc, As + 2048 + wid * 512);
    ASYNC16(Bm + (size_t)(n0 + row4) * ND + k0 + kc, Bs + wid * 512);
    ASYNC16(Bm + (size_t)(n0 + 64 + row4) * ND + k0 + kc, Bs + 2048 + wid * 512);
    __syncthreads();
    const short* as = (const short*)As;
    const short* bs = (const short*)Bs;
    short8 af[4], bq[4];
#pragma unroll
    for (int i = 0; i < 4; ++i) af[i] = *(const short8*)&as[(wm * 64 + i * 16 + c) * 32 + g * 8];
#pragma unroll
    for (int j = 0; j < 4; ++j) bq[j] = *(const short8*)&bs[(wn * 64 + j * 16 + c) * 32 + g * 8];
#pragma unroll
    for (int i = 0; i < 4; ++i)
#pragma unroll
      for (int j = 0; j < 4; ++j)
        acc[i][j] = __builtin_amdgcn_mfma_f32_16x16x32_bf16(af[i], bq[j], acc[i][j], 0, 0, 0);
  }
#pragma unroll
  for (int i = 0; i < 4; ++i) {
    const int mg0 = m0 + wm * 64 + i * 16 + g * 4;
#pragma unroll
    for (int j = 0; j < 4; ++j) {
      const int ng = n0 + wn * 64 + j * 16 + c;
      const int h = ng >> 6, e = ng & 63;
      if (w == 2) {
        const int b = mg0 >> 11, s = mg0 & 2047;
        ushort4 pk = make_ushort4(bf16b(acc[i][j][0]), bf16b(acc[i][j][1]),
                                  bf16b(acc[i][j][2]), bf16b(acc[i][j][3]));
        *(ushort4*)&Vo[(((size_t)b * NH + h) * NE + e) * NS + s] = pk;
      } else {
        bf16* O = (w == 0) ? Qo : Ko;
#pragma unroll
        for (int r = 0; r < 4; ++r) {
          const int m = mg0 + r, b = m >> 11, s = m & 2047;
          O[(((size_t)b * NH + h) * NS + s) * NE + e] = __float2bfloat16(acc[i][j][r]);
        }
      }
    }
  }
}

// ---------------------------------------------------------------------------
// Flash attention (causal). grid (16, 32) ; block 256 = 4 waves, 32 q-rows each.
// Q [B,H,S,E], K [B,H,S,E], V^T [B,H,E,S] -> AO bf16 [B,S,H*E]
// ---------------------------------------------------------------------------
__global__ __launch_bounds__(256) void attn_fwd(const bf16* __restrict__ Qb,
                                                const bf16* __restrict__ Kb,
                                                const bf16* __restrict__ Vt,
                                                bf16* __restrict__ AO) {
  const int bh = blockIdx.y;
  const int q0 = blockIdx.x * 128;
  __shared__ __align__(16) bf16 Qs[128 * 64];
  __shared__ __align__(16) bf16 Ks[128 * 64];
  __shared__ __align__(16) bf16 Vs[64 * 128];
  __shared__ __align__(16) bf16 Ps[4][32 * 128];
  const int tid = threadIdx.x, lane = tid & 63, wid = tid >> 6;
  const int g = lane >> 4, c = lane & 15;
  const bf16* Qg = Qb + ((size_t)bh * NS + q0) * NE;
  const bf16* Kg = Kb + (size_t)bh * NS * NE;
  const bf16* Vg = Vt + (size_t)bh * NE * NS;
#pragma unroll
  for (int i = 0; i < 4; ++i)
    ASYNC16(Qg + (size_t)(i * 32 + (tid >> 3)) * NE + (tid & 7) * 8, Qs + i * 2048 + wid * 512);
  f32x4 acc_o[2][4] = {};
  float mrun[2][4], lrun[2][4];
#pragma unroll
  for (int qm = 0; qm < 2; ++qm)
#pragma unroll
    for (int r = 0; r < 4; ++r) { mrun[qm][r] = -1.0e30f; lrun[qm][r] = 0.f; }
  const int ntile = q0 / 128 + 1;
  for (int tt = 0; tt < ntile; ++tt) {
    const int t0 = tt * 128;
    __syncthreads();
#pragma unroll
    for (int i = 0; i < 4; ++i)
      ASYNC16(Kg + (size_t)(t0 + i * 32 + (tid >> 3)) * NE + (tid & 7) * 8, Ks + i * 2048 + wid * 512);
#pragma unroll
    for (int i = 0; i < 4; ++i)
      ASYNC16(Vg + (size_t)(i * 16 + (tid >> 4)) * NS + t0 + (tid & 15) * 8, Vs + i * 2048 + wid * 512);
    __syncthreads();
    // --- QK^T ---
    f32x4 sacc[2][8] = {};
    const short* qs = (const short*)Qs;
    const short* ks = (const short*)Ks;
#pragma unroll
    for (int kk = 0; kk < 2; ++kk) {
      short8 aq[2], bk[8];
#pragma unroll
      for (int qm = 0; qm < 2; ++qm)
        aq[qm] = *(const short8*)&qs[(wid * 32 + qm * 16 + c) * 64 + kk * 32 + g * 8];
#pragma unroll
      for (int tn = 0; tn < 8; ++tn)
        bk[tn] = *(const short8*)&ks[(tn * 16 + c) * 64 + kk * 32 + g * 8];
#pragma unroll
      for (int qm = 0; qm < 2; ++qm)
#pragma unroll
        for (int tn = 0; tn < 8; ++tn)
          sacc[qm][tn] = __builtin_amdgcn_mfma_f32_16x16x32_bf16(aq[qm], bk[tn], sacc[qm][tn], 0, 0, 0);
    }
    // --- online softmax ---
#pragma unroll
    for (int qm = 0; qm < 2; ++qm) {
      float mx[4] = {-1.0e30f, -1.0e30f, -1.0e30f, -1.0e30f};
#pragma unroll
      for (int tn = 0; tn < 8; ++tn) {
        const int tcol = t0 + tn * 16 + c;
#pragma unroll
        for (int r = 0; r < 4; ++r) {
          const int qrow = q0 + wid * 32 + qm * 16 + g * 4 + r;
          float v = sacc[qm][tn][r] * 0.125f;
          v = (tcol <= qrow) ? v : -1.0e30f;
          sacc[qm][tn][r] = v;
          mx[r] = fmaxf(mx[r], v);
        }
      }
#pragma unroll
      for (int off = 1; off < 16; off <<= 1)
#pragma unroll
        for (int r = 0; r < 4; ++r) mx[r] = fmaxf(mx[r], __shfl_xor(mx[r], off));
      float alpha[4], sum[4] = {0.f, 0.f, 0.f, 0.f};
#pragma unroll
      for (int r = 0; r < 4; ++r) {
        const float mnew = fmaxf(mrun[qm][r], mx[r]);
        alpha[r] = __expf(mrun[qm][r] - mnew);
        mrun[qm][r] = mnew;
      }
#pragma unroll
      for (int tn = 0; tn < 8; ++tn)
#pragma unroll
        for (int r = 0; r < 4; ++r) {
          const float p = __expf(sacc[qm][tn][r] - mrun[qm][r]);
          sacc[qm][tn][r] = p;
          sum[r] += p;
        }
#pragma unroll
      for (int off = 1; off < 16; off <<= 1)
#pragma unroll
        for (int r = 0; r < 4; ++r) sum[r] += __shfl_xor(sum[r], off);
#pragma unroll
      for (int r = 0; r < 4; ++r) lrun[qm][r] = lrun[qm][r] * alpha[r] + sum[r];
#pragma unroll
      for (int fe = 0; fe < 4; ++fe)
#pragma unroll
        for (int r = 0; r < 4; ++r) acc_o[qm][fe][r] *= alpha[r];
#pragma unroll
      for (int tn = 0; tn < 8; ++tn)
#pragma unroll
        for (int r = 0; r < 4; ++r)
          Ps[wid][(qm * 16 + g * 4 + r) * 128 + tn * 16 + c] = __float2bfloat16(sacc[qm][tn][r]);
    }
    __syncthreads();  // P visible cross-lane; Vs still valid
    // --- PV ---
    const short* ps = (const short*)Ps[wid];
    const short* vs = (const short*)Vs;
#pragma unroll
    for (int ks2 = 0; ks2 < 4; ++ks2) {
      short8 ap[2], bv[4];
#pragma unroll
      for (int qm = 0; qm < 2; ++qm)
        ap[qm] = *(const short8*)&ps[(qm * 16 + c) * 128 + ks2 * 32 + g * 8];
#pragma unroll
      for (int fe = 0; fe < 4; ++fe)
        bv[fe] = *(const short8*)&vs[(fe * 16 + c) * 128 + ks2 * 32 + g * 8];
#pragma unroll
      for (int qm = 0; qm < 2; ++qm)
#pragma unroll
        for (int fe = 0; fe < 4; ++fe)
          acc_o[qm][fe] = __builtin_amdgcn_mfma_f32_16x16x32_bf16(ap[qm], bv[fe], acc_o[qm][fe], 0, 0, 0);
    }
  }
  const int b = bh >> 4, h = bh & 15;
#pragma unroll
  for (int qm = 0; qm < 2; ++qm)
#pragma unroll
    for (int fe = 0; fe < 4; ++fe)
#pragma unroll
      for (int r = 0; r < 4; ++r) {
        const int s = q0 + wid * 32 + qm * 16 + g * 4 + r;
        const float val = acc_o[qm][fe][r] / lrun[qm][r];
        AO[((size_t)b * NS + s) * ND + h * NE + fe * 16 + c] = __float2bfloat16(val);
      }
}

// ---------------------------------------------------------------------------
// Output projection: AO bf16 [4096][1024] x Wpb bf16 [n][k] -> out f32
// grid (8, 32), block 256, tile 128x128.
// ---------------------------------------------------------------------------
__global__ __launch_bounds__(256) void proj_gemm(const bf16* __restrict__ A,
                                                 const bf16* __restrict__ Wp,
                                                 float* __restrict__ Y) {
  const int n0 = blockIdx.x * 128, m0 = blockIdx.y * 128;
  __shared__ __align__(16) bf16 As[128 * 32];
  __shared__ __align__(16) bf16 Bs[128 * 32];
  const int tid = threadIdx.x;
  const int lane = tid & 63, wid = tid >> 6;
  const int wm = wid >> 1, wn = wid & 1;
  const int g = lane >> 4, c = lane & 15;
  const int row4 = tid >> 2, kc = (tid & 3) * 8;
  f32x4 acc[4][4] = {};
  for (int k0 = 0; k0 < ND; k0 += 32) {
    __syncthreads();
    ASYNC16(A + (size_t)(m0 + row4) * ND + k0 + kc, As + wid * 512);
    ASYNC16(A + (size_t)(m0 + 64 + row4) * ND + k0 + kc, As + 2048 + wid * 512);
    ASYNC16(Wp + (size_t)(n0 + row4) * ND + k0 + kc, Bs + wid * 512);
    ASYNC16(Wp + (size_t)(n0 + 64 + row4) * ND + k0 + kc, Bs + 2048 + wid * 512);
    __syncthreads();
    const short* as = (const short*)As;
    const short* bs = (const short*)Bs;
    short8 af[4], bq[4];
#pragma unroll
    for (int i = 0; i < 4; ++i) af[i] = *(const short8*)&as[(wm * 64 + i * 16 + c) * 32 + g * 8];
#pragma unroll
    for (int j = 0; j < 4; ++j) bq[j] = *(const short8*)&bs[(wn * 64 + j * 16 + c) * 32 + g * 8];
#pragma unroll
    for (int i = 0; i < 4; ++i)
#pragma unroll
      for (int j = 0; j < 4; ++j)
        acc[i][j] = __builtin_amdgcn_mfma_f32_16x16x32_bf16(af[i], bq[j], acc[i][j], 0, 0, 0);
  }
#pragma unroll
  for (int i = 0; i < 4; ++i) {
    const int mg0 = m0 + wm * 64 + i * 16 + g * 4;
#pragma unroll
    for (int j = 0; j < 4; ++j) {
      const int ng = n0 + wn * 64 + j * 16 + c;
#pragma unroll
      for (int r = 0; r < 4; ++r)
        Y[(size_t)(mg0 + r) * ND + ng] = acc[i][j][r];
    }
  }
}

extern "C" void kernel_launch(void* const* d_in, const int* in_sizes, int n_in,
                              void* d_out, int out_size, void* d_ws, size_t ws_size,
                              hipStream_t stream) {
  const float* x  = (const float*)d_in[0];
  const float* Wq = (const float*)d_in[1];
  const float* Wk = (const float*)d_in[2];
  const float* Wv = (const float*)d_in[3];
  const float* Wp = (const float*)d_in[4];
  float* out = (float*)d_out;            // f32 output (round-7 verified)

  bf16* ws = (bf16*)d_ws;
  bf16* Xb  = ws;                                   // B*S*D     4,194,304
  bf16* WT  = Xb + (size_t)NB * NS * ND;            // 3*H*E*D   3,145,728
  bf16* Wpb = WT + (size_t)3 * NH * NE * ND;        // D*D       1,048,576
  bf16* Qb  = Wpb + (size_t)ND * ND;                // B*H*S*E   4,194,304 each
  bf16* Kb  = Qb + (size_t)NB * NH * NS * NE;
  bf16* Vt  = Kb + (size_t)NB * NH * NS * NE;
  bf16* AO  = Vt + (size_t)NB * NH * NS * NE;

  hipLaunchKernelGGL(ingest_f32_bf16, dim3(2048), dim3(256), 0, stream,
                     x, Xb, NB * NS * ND);
  hipLaunchKernelGGL(ingest_f32_bf16, dim3(512), dim3(256), 0, stream,
                     Wp, Wpb, ND * ND);
  hipLaunchKernelGGL(transpose_w, dim3(256, 3), dim3(256), 0, stream, Wq, Wk, Wv, WT);
  hipLaunchKernelGGL(qkv_gemm, dim3(8, 32, 3), dim3(256), 0, stream, Xb, WT, Qb, Kb, Vt);
  hipLaunchKernelGGL(attn_fwd, dim3(16, 32), dim3(256), 0, stream, Qb, Kb, Vt, AO);
  hipLaunchKernelGGL(proj_gemm, dim3(8, 32), dim3(256), 0, stream, AO, Wpb, out);
}